// Round 1
// baseline (439.438 us; speedup 1.0000x reference)
//
#include <hip/hip_runtime.h>
#include <math.h>

// ---------------------------------------------------------------------------
// MMoE feed-forward, fp32 reference-faithful implementation.
//
// Workspace layout (floats):
//   ctrl   [0 .. 1023]:
//     (int)wsi[0..7]   = slot expert id      (slot s = 2*b + k)
//     (int)wsi[8..15]  = slot batch id
//     wsf[16..23]      = slot gate weight
//     wsf[64..575]     = xp[b][c] pooled means
//   WT   at 1024,                 8 * 294912   (per-slot transposed conv1+conv2 weights)
//   BUF0 at 1024+2359296,         8 * 524288   (slot input / conv2 output)
//   BUF1 at BUF0 + 4194304,       8 * 524288   (conv1 output; later aliased as YBUF)
// total = 10,748,928 floats = ~43 MB
// ---------------------------------------------------------------------------

#define SLOT_BUF 524288      // 128*64*64
#define WT_SLOT  294912      // 2 * 128*128*9
#define CONV_W   147456      // 128*128*9

// ---------------- xp: per-(b,c) spatial mean --------------------------------
__global__ __launch_bounds__(256) void xp_kernel(const float* __restrict__ x,
                                                 float* __restrict__ wsf) {
  int k = blockIdx.x;                       // b*128 + c, 512 blocks
  const float4* p = (const float4*)(x + (size_t)k * 1024);
  float4 v = p[threadIdx.x];
  float s = v.x + v.y + v.z + v.w;
  #pragma unroll
  for (int off = 32; off > 0; off >>= 1) s += __shfl_down(s, off);
  __shared__ float red[4];
  if ((threadIdx.x & 63) == 0) red[threadIdx.x >> 6] = s;
  __syncthreads();
  if (threadIdx.x == 0)
    wsf[64 + k] = (red[0] + red[1] + red[2] + red[3]) * (1.0f / 1024.0f);
}

// ---------------- gate: logits -> softmax -> top2 -> slots + MI loss --------
__global__ void gate_kernel(const float* __restrict__ tf,
                            const float* __restrict__ Wx,
                            const float* __restrict__ Wt,
                            float* __restrict__ wsf,
                            float* __restrict__ out) {
  int tid = threadIdx.x;                    // 64 threads: (b, e)
  int b = tid >> 4, e = tid & 15;
  __shared__ float slog[64];
  __shared__ float sprob[64];
  const float* xp = wsf + 64;

  float acc = 0.0f;
  for (int c = 0; c < 128; ++c) acc += xp[b * 128 + c] * Wx[c * 16 + e];
  for (int d = 0; d < 512; ++d) acc += tf[b * 512 + d] * Wt[d * 16 + e];
  slog[tid] = acc;
  __syncthreads();

  float m = slog[b * 16];
  for (int j = 1; j < 16; ++j) m = fmaxf(m, slog[b * 16 + j]);
  float ex = expf(acc - m);
  sprob[tid] = ex;
  __syncthreads();
  float s = 0.0f;
  for (int j = 0; j < 16; ++j) s += sprob[b * 16 + j];
  float p = ex / s;
  __syncthreads();
  sprob[tid] = p;
  __syncthreads();

  if (e == 0) {
    int i1 = 0; float v1 = -1.0f;
    for (int j = 0; j < 16; ++j) {
      float v = sprob[b * 16 + j];
      if (v > v1) { v1 = v; i1 = j; }
    }
    int i2 = -1; float v2 = -1.0f;
    for (int j = 0; j < 16; ++j) {
      if (j == i1) continue;
      float v = sprob[b * 16 + j];
      if (v > v2) { v2 = v; i2 = j; }
    }
    float inv = 1.0f / (v1 + v2);
    int* wsi = (int*)wsf;
    wsi[2 * b]     = i1;  wsi[2 * b + 1]     = i2;
    wsi[8 + 2 * b] = b;   wsi[8 + 2 * b + 1] = b;
    wsf[16 + 2 * b]     = v1 * inv;
    wsf[16 + 2 * b + 1] = v2 * inv;
  }
  __syncthreads();
  if (tid == 0) {
    float kl = 0.0f;
    for (int j = 0; j < 16; ++j) {
      float pe = 0.25f * (sprob[j] + sprob[16 + j] + sprob[32 + j] + sprob[48 + j]);
      kl += pe * logf(pe / (pe + 1e-7f) + 1e-7f);
    }
    out[524288] = -0.01f * kl;              // mi_loss
  }
}

// ---------------- per-slot weight transpose: [oc][ic][tap] -> [ic][tap][oc] -
__global__ __launch_bounds__(256) void wtrans_kernel(const float* __restrict__ ctrl,
                                                     const float* __restrict__ cw1,
                                                     const float* __restrict__ cw2,
                                                     float* __restrict__ wt) {
  const int* wsi = (const int*)ctrl;
  int slot = blockIdx.y;
  int e = wsi[slot];
  int idx = blockIdx.x * 256 + threadIdx.x;   // < 294912 (grid.x = 1152)
  int which = idx / CONV_W;
  int r = idx - which * CONV_W;               // (ic*9+tap)*128 + oc
  int oc = r & 127;
  int q = r >> 7;
  int tap = q % 9, ic = q / 9;
  const float* src = which ? cw2 : cw1;
  wt[(size_t)slot * WT_SLOT + idx] =
      src[(((size_t)e * 128 + oc) * 128 + ic) * 9 + tap];
}

// ---------------- prep: copy / nearest-up(x2) / maxpool(2) ------------------
__global__ __launch_bounds__(256) void prep_kernel(const float* __restrict__ ctrl,
                                                   const float* __restrict__ x,
                                                   float* __restrict__ buf0) {
  const int* wsi = (const int*)ctrl;
  int slot = blockIdx.y;
  int e = wsi[slot];
  int b = wsi[8 + slot];
  int tp = e % 3;
  int S = (tp == 0) ? 32 : ((tp == 1) ? 64 : 16);
  int N = 128 * S * S;
  int idx = blockIdx.x * 256 + threadIdx.x;
  if (idx >= N) return;
  int c = idx / (S * S);
  int rem = idx - c * (S * S);
  int h = rem / S, w = rem - (rem / S) * S;
  const float* xb = x + (size_t)b * 131072;
  float v;
  if (tp == 0) {
    v = xb[idx];
  } else if (tp == 1) {
    v = xb[c * 1024 + (h >> 1) * 32 + (w >> 1)];
  } else {
    const float* p = xb + c * 1024 + (h << 1) * 32 + (w << 1);
    v = fmaxf(fmaxf(p[0], p[1]), fmaxf(p[32], p[33]));
  }
  buf0[(size_t)slot * SLOT_BUF + idx] = v;
}

// ---------------- conv3x3 + bias (+ exact GELU) ------------------------------
#define ICB 16
__global__ __launch_bounds__(256) void conv_kernel(const float* __restrict__ ctrl,
                                                   const float* __restrict__ bufin,
                                                   float* __restrict__ bufout,
                                                   const float* __restrict__ wt,
                                                   int woff,
                                                   const float* __restrict__ ball,
                                                   int gelu) {
  const int* wsi = (const int*)ctrl;
  int slot = blockIdx.x >> 1;
  int ocb = (blockIdx.x & 1) << 6;          // 0 or 64
  int e = wsi[slot];
  int tp = e % 3;
  int S = (tp == 0) ? 32 : ((tp == 1) ? 64 : 16);
  int tpr = S >> 3;
  int tile = blockIdx.y;
  if (tile >= tpr * tpr) return;
  int tr = (tile / tpr) << 3;
  int tc = (tile % tpr) << 3;

  const float* in  = bufin  + (size_t)slot * SLOT_BUF;
  float*       outp= bufout + (size_t)slot * SLOT_BUF;
  const float* wts = wt + (size_t)slot * WT_SLOT + woff;
  const float* bias = ball + e * 128;

  __shared__ float slds[ICB][10][12];
  __shared__ float wlds[ICB][9][64];

  int tid = threadIdx.x;
  int pxg = tid & 15;                        // 16 pixel groups
  int ocg = tid >> 4;                        // 16 oc groups
  int r  = pxg >> 1;                         // 0..7 tile row
  int c0 = (pxg & 1) << 2;                   // 0 or 4
  int oc0 = ocb + (ocg << 2);

  float acc[4][4];
  #pragma unroll
  for (int j = 0; j < 4; ++j) {
    float bv = bias[oc0 + j];
    #pragma unroll
    for (int p = 0; p < 4; ++p) acc[j][p] = bv;
  }

  for (int ic0 = 0; ic0 < 128; ic0 += ICB) {
    __syncthreads();
    // stage input tile + halo (zero 'SAME' padding)
    for (int idx = tid; idx < ICB * 100; idx += 256) {
      int icl = idx / 100;
      int rem = idx - icl * 100;
      int rr = rem / 10, cc = rem - (rem / 10) * 10;
      int gr = tr + rr - 1, gc = tc + cc - 1;
      float v = 0.0f;
      if (gr >= 0 && gr < S && gc >= 0 && gc < S)
        v = in[(size_t)(ic0 + icl) * S * S + gr * S + gc];
      slds[icl][rr][cc] = v;
    }
    // stage weights [icl][tap][oc]: coalesced global, linear LDS
    for (int idx = tid; idx < ICB * 9 * 64; idx += 256) {
      int ocl = idx & 63;
      int rem = idx >> 6;
      int tap = rem % 9, icl = rem / 9;
      wlds[icl][tap][ocl] = wts[((ic0 + icl) * 9 + tap) * 128 + ocb + ocl];
    }
    __syncthreads();

    #pragma unroll 4
    for (int icl = 0; icl < ICB; ++icl) {
      #pragma unroll
      for (int dr = 0; dr < 3; ++dr) {
        float rowv[6];
        #pragma unroll
        for (int q = 0; q < 6; ++q) rowv[q] = slds[icl][r + dr][c0 + q];
        #pragma unroll
        for (int dc = 0; dc < 3; ++dc) {
          float wv[4];
          #pragma unroll
          for (int j = 0; j < 4; ++j) wv[j] = wlds[icl][dr * 3 + dc][(ocg << 2) + j];
          #pragma unroll
          for (int j = 0; j < 4; ++j)
            #pragma unroll
            for (int p = 0; p < 4; ++p)
              acc[j][p] += wv[j] * rowv[dc + p];
        }
      }
    }
  }

  #pragma unroll
  for (int j = 0; j < 4; ++j) {
    #pragma unroll
    for (int p = 0; p < 4; ++p) {
      float v = acc[j][p];
      if (gelu) v = 0.5f * v * (1.0f + erff(v * 0.70710678118654752f));
      outp[(size_t)(oc0 + j) * S * S + (tr + r) * S + (tc + c0 + p)] = v;
    }
  }
}

// ---------------- post: identity / maxpool / bilinear-up, * gate ------------
__global__ __launch_bounds__(256) void post_kernel(const float* __restrict__ ctrl,
                                                   const float* __restrict__ buf0,
                                                   float* __restrict__ ybuf) {
  const int* wsi = (const int*)ctrl;
  int slot = blockIdx.y;
  int e = wsi[slot];
  float g = ctrl[16 + slot];
  int tp = e % 3;
  int idx = blockIdx.x * 256 + threadIdx.x;   // < 131072
  int c = idx >> 10;
  int rem = idx & 1023;
  int h = rem >> 5, w = rem & 31;
  const float* cin = buf0 + (size_t)slot * SLOT_BUF;
  float v;
  if (tp == 0) {
    v = cin[idx];
  } else if (tp == 1) {                       // maxpool from 64x64
    const float* p = cin + c * 4096 + (h << 1) * 64 + (w << 1);
    v = fmaxf(fmaxf(p[0], p[1]), fmaxf(p[64], p[65]));
  } else {                                    // half-pixel bilinear from 16x16
    float sh = h * 0.5f - 0.25f, sw = w * 0.5f - 0.25f;
    int h0 = (int)floorf(sh), w0 = (int)floorf(sw);
    float fh = sh - (float)h0, fw = sw - (float)w0;
    int h0c = h0 < 0 ? 0 : h0, h1c = (h0 + 1 > 15) ? 15 : h0 + 1;
    int w0c = w0 < 0 ? 0 : w0, w1c = (w0 + 1 > 15) ? 15 : w0 + 1;
    const float* p = cin + c * 256;
    float a00 = p[h0c * 16 + w0c], a01 = p[h0c * 16 + w1c];
    float a10 = p[h1c * 16 + w0c], a11 = p[h1c * 16 + w1c];
    v = (1.0f - fh) * ((1.0f - fw) * a00 + fw * a01) +
        fh * ((1.0f - fw) * a10 + fw * a11);
  }
  ybuf[(size_t)slot * SLOT_BUF + idx] = g * v;
}

// ---------------- combine: out[b] = y[slot 2b] + y[slot 2b+1] ---------------
__global__ __launch_bounds__(256) void combine_kernel(const float* __restrict__ ybuf,
                                                      float* __restrict__ out) {
  int idx = blockIdx.x * 256 + threadIdx.x;   // < 524288
  int b = idx >> 17, r = idx & 131071;
  out[idx] = ybuf[(size_t)(2 * b) * SLOT_BUF + r] +
             ybuf[(size_t)(2 * b + 1) * SLOT_BUF + r];
}

// ---------------------------------------------------------------------------
extern "C" void kernel_launch(void* const* d_in, const int* in_sizes, int n_in,
                              void* d_out, int out_size, void* d_ws, size_t ws_size,
                              hipStream_t stream) {
  const float* x   = (const float*)d_in[0];
  const float* tf  = (const float*)d_in[1];
  const float* Wx  = (const float*)d_in[2];
  const float* Wt  = (const float*)d_in[3];
  const float* cw1 = (const float*)d_in[4];
  const float* cb1 = (const float*)d_in[5];
  const float* cw2 = (const float*)d_in[6];
  const float* cb2 = (const float*)d_in[7];
  float* out = (float*)d_out;

  float* wsf  = (float*)d_ws;
  float* wt   = wsf + 1024;
  float* buf0 = wt + 8 * WT_SLOT;
  float* buf1 = buf0 + 8 * SLOT_BUF;
  float* ybuf = buf1;                         // alias: conv1 output dead by post

  hipLaunchKernelGGL(xp_kernel,      dim3(512),      dim3(256), 0, stream, x, wsf);
  hipLaunchKernelGGL(gate_kernel,    dim3(1),        dim3(64),  0, stream, tf, Wx, Wt, wsf, out);
  hipLaunchKernelGGL(wtrans_kernel,  dim3(1152, 8),  dim3(256), 0, stream, wsf, cw1, cw2, wt);
  hipLaunchKernelGGL(prep_kernel,    dim3(2048, 8),  dim3(256), 0, stream, wsf, x, buf0);
  hipLaunchKernelGGL(conv_kernel,    dim3(16, 64),   dim3(256), 0, stream, wsf, buf0, buf1, wt, 0,      cb1, 1);
  hipLaunchKernelGGL(conv_kernel,    dim3(16, 64),   dim3(256), 0, stream, wsf, buf1, buf0, wt, CONV_W, cb2, 0);
  hipLaunchKernelGGL(post_kernel,    dim3(512, 8),   dim3(256), 0, stream, wsf, buf0, ybuf);
  hipLaunchKernelGGL(combine_kernel, dim3(2048),     dim3(256), 0, stream, ybuf, out);
}

// Round 2
// 121.953 us; speedup vs baseline: 3.6033x; 3.6033x over previous
//
#include <hip/hip_runtime.h>
#include <math.h>

// ---------------------------------------------------------------------------
// MMoE feed-forward: bf16 NHWC + MFMA implicit-GEMM conv.
//
// ws layout (elements):
//   wsf (f32) [0..1023]: wsi[0..7]=slot expert, wsi[8..15]=slot batch,
//                        wsf[16..23]=gate, wsf[64..575]=xp
//   wt2 (bf16)  8 * 294912   per-slot weights [which][tap][oc][ic]
//   buf0 (bf16) 8 * 524288   NHWC slot buffers
//   buf1 (bf16) 8 * 524288
// ---------------------------------------------------------------------------

typedef __attribute__((ext_vector_type(8))) short bf16x8;
typedef __attribute__((ext_vector_type(4))) float f32x4;

#define SLOT_ELEMS 524288            // 128*64*64
#define WT_ELEMS   294912            // 2*9*128*128

__device__ inline ushort f2bf(float f) {
  unsigned u = __float_as_uint(f);
  return (ushort)((u + 0x7FFFu + ((u >> 16) & 1u)) >> 16);
}
__device__ inline float bf2f(ushort h) {
  return __uint_as_float(((unsigned)h) << 16);
}

// ---------------- xp: per-(b,c) spatial mean --------------------------------
__global__ __launch_bounds__(256) void xp_kernel(const float* __restrict__ x,
                                                 float* __restrict__ wsf) {
  int k = blockIdx.x;                       // b*128 + c
  const float4* p = (const float4*)(x + (size_t)k * 1024);
  float4 v = p[threadIdx.x];
  float s = v.x + v.y + v.z + v.w;
  #pragma unroll
  for (int off = 32; off > 0; off >>= 1) s += __shfl_down(s, off);
  __shared__ float red[4];
  if ((threadIdx.x & 63) == 0) red[threadIdx.x >> 6] = s;
  __syncthreads();
  if (threadIdx.x == 0)
    wsf[64 + k] = (red[0] + red[1] + red[2] + red[3]) * (1.0f / 1024.0f);
}

// ---------------- gate ------------------------------------------------------
__global__ void gate_kernel(const float* __restrict__ tf,
                            const float* __restrict__ Wx,
                            const float* __restrict__ Wt,
                            float* __restrict__ wsf,
                            float* __restrict__ out) {
  int tid = threadIdx.x;                    // 64 threads: (b, e)
  int b = tid >> 4, e = tid & 15;
  __shared__ float slog[64];
  __shared__ float sprob[64];
  const float* xp = wsf + 64;

  float acc = 0.0f;
  for (int c = 0; c < 128; ++c) acc += xp[b * 128 + c] * Wx[c * 16 + e];
  for (int d = 0; d < 512; ++d) acc += tf[b * 512 + d] * Wt[d * 16 + e];
  slog[tid] = acc;
  __syncthreads();

  float m = slog[b * 16];
  for (int j = 1; j < 16; ++j) m = fmaxf(m, slog[b * 16 + j]);
  float ex = expf(acc - m);
  sprob[tid] = ex;
  __syncthreads();
  float s = 0.0f;
  for (int j = 0; j < 16; ++j) s += sprob[b * 16 + j];
  float p = ex / s;
  __syncthreads();
  sprob[tid] = p;
  __syncthreads();

  if (e == 0) {
    int i1 = 0; float v1 = -1.0f;
    for (int j = 0; j < 16; ++j) {
      float v = sprob[b * 16 + j];
      if (v > v1) { v1 = v; i1 = j; }
    }
    int i2 = -1; float v2 = -1.0f;
    for (int j = 0; j < 16; ++j) {
      if (j == i1) continue;
      float v = sprob[b * 16 + j];
      if (v > v2) { v2 = v; i2 = j; }
    }
    float inv = 1.0f / (v1 + v2);
    int* wsi = (int*)wsf;
    wsi[2 * b]     = i1;  wsi[2 * b + 1]     = i2;
    wsi[8 + 2 * b] = b;   wsi[8 + 2 * b + 1] = b;
    wsf[16 + 2 * b]     = v1 * inv;
    wsf[16 + 2 * b + 1] = v2 * inv;
  }
  __syncthreads();
  if (tid == 0) {
    float kl = 0.0f;
    for (int j = 0; j < 16; ++j) {
      float pe = 0.25f * (sprob[j] + sprob[16 + j] + sprob[32 + j] + sprob[48 + j]);
      kl += pe * logf(pe / (pe + 1e-7f) + 1e-7f);
    }
    out[524288] = -0.01f * kl;              // mi_loss
  }
}

// ---------------- wtrans: cw[e][oc][ic][tap] f32 -> [which][tap][oc][ic] bf16
__global__ __launch_bounds__(256) void wtrans_kernel(const float* __restrict__ ctrl,
                                                     const float* __restrict__ cw1,
                                                     const float* __restrict__ cw2,
                                                     ushort* __restrict__ wt) {
  const int* wsi = (const int*)ctrl;
  int slot = blockIdx.y;
  int e = wsi[slot];
  int idx = blockIdx.x * 256 + threadIdx.x;   // < 294912
  int which = idx / 147456;
  int r = idx - which * 147456;               // (tap*128+oc)*128+ic
  int ic = r & 127;
  int q = r >> 7;
  int oc = q & 127, tap = q >> 7;
  const float* src = which ? cw2 : cw1;
  wt[(size_t)slot * WT_ELEMS + idx] =
      f2bf(src[(((size_t)e * 128 + oc) * 128 + ic) * 9 + tap]);
}

// ---------------- prep: NCHW f32 (+spatial xform) -> NHWC bf16 --------------
__global__ __launch_bounds__(256) void prep_kernel(const float* __restrict__ ctrl,
                                                   const float* __restrict__ x,
                                                   ushort* __restrict__ buf0) {
  const int* wsi = (const int*)ctrl;
  int slot = blockIdx.y;
  int e = wsi[slot];
  int b = wsi[8 + slot];
  int tp = e % 3;
  int S = (tp == 0) ? 32 : ((tp == 1) ? 64 : 16);
  int chunk = blockIdx.x;
  if (chunk * 64 >= S * S) return;

  __shared__ float sT[128 * 65];
  int tid = threadIdx.x;
  const float* xb = x + (size_t)b * 131072;
  int pxl0 = tid & 63, c0 = tid >> 6;

  #pragma unroll 4
  for (int i = 0; i < 32; ++i) {
    int c = i * 4 + c0;
    int px = chunk * 64 + pxl0;
    float v;
    if (tp == 0) {
      v = xb[c * 1024 + px];
    } else if (tp == 1) {
      int h = px >> 6, w = px & 63;
      v = xb[c * 1024 + (h >> 1) * 32 + (w >> 1)];
    } else {
      int h = px >> 4, w = px & 15;
      const float* p = xb + c * 1024 + (h << 1) * 32 + (w << 1);
      v = fmaxf(fmaxf(p[0], p[1]), fmaxf(p[32], p[33]));
    }
    sT[c * 65 + pxl0] = v;
  }
  __syncthreads();
  ushort* ob = buf0 + (size_t)slot * SLOT_ELEMS;
  #pragma unroll
  for (int i = 0; i < 4; ++i) {
    int u = i * 256 + tid;
    int pxl = u >> 4, q = u & 15;
    bf16x8 pk;
    #pragma unroll
    for (int j = 0; j < 8; ++j) pk[j] = (short)f2bf(sT[(q * 8 + j) * 65 + pxl]);
    *(bf16x8*)&ob[(size_t)(chunk * 64 + pxl) * 128 + q * 8] = pk;
  }
}

// ---------------- conv3x3 via MFMA implicit GEMM ----------------------------
// block: 128 oc x 64 px (8x8 tile); 4 waves, each 32 oc x 64 px
__global__ __launch_bounds__(256, 4) void conv_mfma(const float* __restrict__ ctrl,
                                                    const ushort* __restrict__ bufin,
                                                    ushort* __restrict__ bufout,
                                                    const ushort* __restrict__ wt,
                                                    int which,
                                                    const float* __restrict__ ball,
                                                    int gelu) {
  const int* wsi = (const int*)ctrl;
  int slot = blockIdx.x;
  int e = wsi[slot];
  int tp = e % 3;
  int S = (tp == 0) ? 32 : ((tp == 1) ? 64 : 16);
  int tpr = S >> 3;
  int tile = blockIdx.y;
  if (tile >= tpr * tpr) return;
  int tr = (tile / tpr) << 3;
  int tc = (tile % tpr) << 3;

  __shared__ ushort sIn[10 * 10 * 136];   // [halo px][128 ch + 8 pad]
  __shared__ ushort sW[128 * 40];         // [oc][32 ic + 8 pad]

  int tid = threadIdx.x;
  const ushort* in = bufin + (size_t)slot * SLOT_ELEMS;

  // stage input tile + halo (all 128 ch), zero padding
  for (int u = tid; u < 1600; u += 256) {
    int p = u >> 4, q = u & 15;
    int hr = p / 10, wc = p - hr * 10;
    int gh = tr + hr - 1, gw = tc + wc - 1;
    bf16x8 v = {0, 0, 0, 0, 0, 0, 0, 0};
    if (gh >= 0 && gh < S && gw >= 0 && gw < S)
      v = *(const bf16x8*)&in[(size_t)(gh * S + gw) * 128 + q * 8];
    *(bf16x8*)&sIn[p * 136 + q * 8] = v;
  }

  int wid = tid >> 6, lane = tid & 63;
  int ln = lane & 15, lg = lane >> 4;
  int ocw = wid << 5;

  f32x4 acc[2][4];
  #pragma unroll
  for (int m = 0; m < 2; ++m)
    #pragma unroll
    for (int n = 0; n < 4; ++n)
      #pragma unroll
      for (int j = 0; j < 4; ++j) acc[m][n][j] = 0.0f;

  int arow[2], pxb[4];
  #pragma unroll
  for (int m = 0; m < 2; ++m) arow[m] = (ocw + m * 16 + ln) * 40 + lg * 8;
  #pragma unroll
  for (int n = 0; n < 4; ++n) {
    int px = n * 16 + ln;
    pxb[n] = (px >> 3) * 10 + (px & 7);
  }

  const ushort* wts = wt + (size_t)slot * WT_ELEMS + (size_t)which * 147456;

  for (int tap = 0; tap < 9; ++tap) {
    int off = (tap / 3) * 10 + (tap % 3);   // dr*10+dc
    for (int icc = 0; icc < 4; ++icc) {
      __syncthreads();
      #pragma unroll
      for (int u = tid; u < 512; u += 256) {
        int oc = u >> 2, q = u & 3;
        *(bf16x8*)&sW[oc * 40 + q * 8] =
            *(const bf16x8*)&wts[(size_t)(tap * 128 + oc) * 128 + icc * 32 + q * 8];
      }
      __syncthreads();
      bf16x8 afr[2], bfr[4];
      #pragma unroll
      for (int m = 0; m < 2; ++m) afr[m] = *(bf16x8*)&sW[arow[m]];
      #pragma unroll
      for (int n = 0; n < 4; ++n)
        bfr[n] = *(bf16x8*)&sIn[(pxb[n] + off) * 136 + icc * 32 + lg * 8];
      #pragma unroll
      for (int m = 0; m < 2; ++m)
        #pragma unroll
        for (int n = 0; n < 4; ++n)
          acc[m][n] = __builtin_amdgcn_mfma_f32_16x16x32_bf16(afr[m], bfr[n],
                                                              acc[m][n], 0, 0, 0);
    }
  }

  // epilogue: bias (+gelu), pack bf16, NHWC store
  ushort* outp = bufout + (size_t)slot * SLOT_ELEMS;
  const float* bias = ball + e * 128;
  #pragma unroll
  for (int m = 0; m < 2; ++m) {
    int oc0 = ocw + m * 16 + lg * 4;
    float bv[4];
    #pragma unroll
    for (int j = 0; j < 4; ++j) bv[j] = bias[oc0 + j];
    #pragma unroll
    for (int n = 0; n < 4; ++n) {
      int px = n * 16 + ln;
      int gh = tr + (px >> 3), gw = tc + (px & 7);
      unsigned pk0, pk1;
      float v0 = acc[m][n][0] + bv[0];
      float v1 = acc[m][n][1] + bv[1];
      float v2 = acc[m][n][2] + bv[2];
      float v3 = acc[m][n][3] + bv[3];
      if (gelu) {
        v0 = 0.5f * v0 * (1.0f + erff(v0 * 0.70710678118654752f));
        v1 = 0.5f * v1 * (1.0f + erff(v1 * 0.70710678118654752f));
        v2 = 0.5f * v2 * (1.0f + erff(v2 * 0.70710678118654752f));
        v3 = 0.5f * v3 * (1.0f + erff(v3 * 0.70710678118654752f));
      }
      pk0 = (unsigned)f2bf(v0) | ((unsigned)f2bf(v1) << 16);
      pk1 = (unsigned)f2bf(v2) | ((unsigned)f2bf(v3) << 16);
      uint2 st; st.x = pk0; st.y = pk1;
      *(uint2*)&outp[(size_t)(gh * S + gw) * 128 + oc0] = st;
    }
  }
}

// ---------------- combine: post-transform * gate, NHWC bf16 -> NCHW f32 -----
__global__ __launch_bounds__(256) void combine_kernel(const float* __restrict__ ctrl,
                                                      const ushort* __restrict__ bufc,
                                                      float* __restrict__ out) {
  const int* wsi = (const int*)ctrl;
  int b = blockIdx.y, chunk = blockIdx.x;
  __shared__ float sO[64 * 129];
  int tid = threadIdx.x;

  #pragma unroll
  for (int i = 0; i < 4; ++i) {
    int u = i * 256 + tid;
    int pxl = u >> 4, q = u & 15;
    int px = chunk * 64 + pxl;
    int h = px >> 5, w = px & 31;
    float a8[8];
    #pragma unroll
    for (int j = 0; j < 8; ++j) a8[j] = 0.0f;

    for (int s = 0; s < 2; ++s) {
      int slot = 2 * b + s;
      int e = wsi[slot];
      float g = ctrl[16 + slot];
      int tp = e % 3;
      const ushort* cin = bufc + (size_t)slot * SLOT_ELEMS;
      if (tp == 0) {
        bf16x8 v = *(const bf16x8*)&cin[(size_t)(h * 32 + w) * 128 + q * 8];
        #pragma unroll
        for (int j = 0; j < 8; ++j) a8[j] += g * bf2f((ushort)v[j]);
      } else if (tp == 1) {                 // maxpool from 64x64
        bf16x8 v00 = *(const bf16x8*)&cin[(size_t)((2*h) * 64 + 2*w) * 128 + q * 8];
        bf16x8 v01 = *(const bf16x8*)&cin[(size_t)((2*h) * 64 + 2*w + 1) * 128 + q * 8];
        bf16x8 v10 = *(const bf16x8*)&cin[(size_t)((2*h+1) * 64 + 2*w) * 128 + q * 8];
        bf16x8 v11 = *(const bf16x8*)&cin[(size_t)((2*h+1) * 64 + 2*w + 1) * 128 + q * 8];
        #pragma unroll
        for (int j = 0; j < 8; ++j) {
          float mv = fmaxf(fmaxf(bf2f((ushort)v00[j]), bf2f((ushort)v01[j])),
                           fmaxf(bf2f((ushort)v10[j]), bf2f((ushort)v11[j])));
          a8[j] += g * mv;
        }
      } else {                              // bilinear up from 16x16
        float sh = h * 0.5f - 0.25f, sw = w * 0.5f - 0.25f;
        float fh0 = floorf(sh), fw0 = floorf(sw);
        int h0 = (int)fh0, w0 = (int)fw0;
        float fh = sh - fh0, fw = sw - fw0;
        int h0c = h0 < 0 ? 0 : h0, h1c = (h0 + 1 > 15) ? 15 : h0 + 1;
        int w0c = w0 < 0 ? 0 : w0, w1c = (w0 + 1 > 15) ? 15 : w0 + 1;
        bf16x8 v00 = *(const bf16x8*)&cin[(size_t)(h0c * 16 + w0c) * 128 + q * 8];
        bf16x8 v01 = *(const bf16x8*)&cin[(size_t)(h0c * 16 + w1c) * 128 + q * 8];
        bf16x8 v10 = *(const bf16x8*)&cin[(size_t)(h1c * 16 + w0c) * 128 + q * 8];
        bf16x8 v11 = *(const bf16x8*)&cin[(size_t)(h1c * 16 + w1c) * 128 + q * 8];
        #pragma unroll
        for (int j = 0; j < 8; ++j) {
          float vv = (1.0f - fh) * ((1.0f - fw) * bf2f((ushort)v00[j]) + fw * bf2f((ushort)v01[j])) +
                     fh * ((1.0f - fw) * bf2f((ushort)v10[j]) + fw * bf2f((ushort)v11[j]));
          a8[j] += g * vv;
        }
      }
    }
    #pragma unroll
    for (int j = 0; j < 8; ++j) sO[pxl * 129 + q * 8 + j] = a8[j];
  }
  __syncthreads();
  float* ob = out + (size_t)b * 131072;
  #pragma unroll 4
  for (int i = 0; i < 32; ++i) {
    int u = i * 256 + tid;
    int c = u >> 6, pxl = u & 63;
    ob[(size_t)c * 1024 + chunk * 64 + pxl] = sO[pxl * 129 + c];
  }
}

// ---------------------------------------------------------------------------
extern "C" void kernel_launch(void* const* d_in, const int* in_sizes, int n_in,
                              void* d_out, int out_size, void* d_ws, size_t ws_size,
                              hipStream_t stream) {
  const float* x   = (const float*)d_in[0];
  const float* tf  = (const float*)d_in[1];
  const float* Wx  = (const float*)d_in[2];
  const float* Wt  = (const float*)d_in[3];
  const float* cw1 = (const float*)d_in[4];
  const float* cb1 = (const float*)d_in[5];
  const float* cw2 = (const float*)d_in[6];
  const float* cb2 = (const float*)d_in[7];
  float* out = (float*)d_out;

  float*  wsf  = (float*)d_ws;
  ushort* wt2  = (ushort*)(wsf + 1024);
  ushort* buf0 = wt2 + 8 * (size_t)WT_ELEMS;
  ushort* buf1 = buf0 + 8 * (size_t)SLOT_ELEMS;

  hipLaunchKernelGGL(xp_kernel,      dim3(512),     dim3(256), 0, stream, x, wsf);
  hipLaunchKernelGGL(gate_kernel,    dim3(1),       dim3(64),  0, stream, tf, Wx, Wt, wsf, out);
  hipLaunchKernelGGL(wtrans_kernel,  dim3(1152, 8), dim3(256), 0, stream, wsf, cw1, cw2, wt2);
  hipLaunchKernelGGL(prep_kernel,    dim3(64, 8),   dim3(256), 0, stream, wsf, x, buf0);
  hipLaunchKernelGGL(conv_mfma,      dim3(8, 64),   dim3(256), 0, stream, wsf, buf0, buf1, wt2, 0, cb1, 1);
  hipLaunchKernelGGL(conv_mfma,      dim3(8, 64),   dim3(256), 0, stream, wsf, buf1, buf0, wt2, 1, cb2, 0);
  hipLaunchKernelGGL(combine_kernel, dim3(16, 4),   dim3(256), 0, stream, wsf, buf0, out);
}

// Round 3
// 99.796 us; speedup vs baseline: 4.4034x; 1.2220x over previous
//
#include <hip/hip_runtime.h>
#include <math.h>

// ---------------------------------------------------------------------------
// MMoE feed-forward: bf16 NHWC + MFMA implicit-GEMM conv.
// Round 2: fragment-ordered weights (coalesced global A-frag loads, no weight
// LDS staging, barrier-free K-loop), parallelized gate.
//
// ws layout (elements):
//   wsf (f32) [0..1023]: wsi[0..7]=slot expert, wsi[8..15]=slot batch,
//                        wsf[16..23]=gate, wsf[64..575]=xp
//   wt2 (bf16)  8 * 294912   per-slot weights, MFMA-frag order:
//               [which][k=tap*4+icc][oc16blk(0..7)][lane(0..63)][j(0..7)]
//               value = W[oc=blk*16+(lane&15)][ic=icc*32+(lane>>4)*8+j]
//   buf0 (bf16) 8 * 524288   NHWC slot buffers
//   buf1 (bf16) 8 * 524288
// ---------------------------------------------------------------------------

typedef __attribute__((ext_vector_type(8))) short bf16x8;
typedef __attribute__((ext_vector_type(4))) float f32x4;

#define SLOT_ELEMS 524288            // 128*64*64
#define WT_ELEMS   294912            // 2*9*128*128

__device__ inline ushort f2bf(float f) {
  unsigned u = __float_as_uint(f);
  return (ushort)((u + 0x7FFFu + ((u >> 16) & 1u)) >> 16);
}
__device__ inline float bf2f(ushort h) {
  return __uint_as_float(((unsigned)h) << 16);
}

// ---------------- xp: per-(b,c) spatial mean --------------------------------
__global__ __launch_bounds__(256) void xp_kernel(const float* __restrict__ x,
                                                 float* __restrict__ wsf) {
  int k = blockIdx.x;                       // b*128 + c
  const float4* p = (const float4*)(x + (size_t)k * 1024);
  float4 v = p[threadIdx.x];
  float s = v.x + v.y + v.z + v.w;
  #pragma unroll
  for (int off = 32; off > 0; off >>= 1) s += __shfl_down(s, off);
  __shared__ float red[4];
  if ((threadIdx.x & 63) == 0) red[threadIdx.x >> 6] = s;
  __syncthreads();
  if (threadIdx.x == 0)
    wsf[64 + k] = (red[0] + red[1] + red[2] + red[3]) * (1.0f / 1024.0f);
}

// ---------------- gate ------------------------------------------------------
__global__ __launch_bounds__(256) void gate_kernel(const float* __restrict__ tf,
                                                   const float* __restrict__ Wx,
                                                   const float* __restrict__ Wt,
                                                   float* __restrict__ wsf,
                                                   float* __restrict__ out) {
  __shared__ float part[4][64];
  __shared__ float slog[64];
  __shared__ float sprob[64];
  __shared__ float ssum[4];
  int tid = threadIdx.x;
  int p = tid >> 6, be = tid & 63;
  int b = be >> 4, e = be & 15;
  const float* xp = wsf + 64;

  float acc = 0.0f;
  for (int c = p * 32; c < p * 32 + 32; ++c) acc += xp[b * 128 + c] * Wx[c * 16 + e];
  for (int d = p * 128; d < p * 128 + 128; ++d) acc += tf[b * 512 + d] * Wt[d * 16 + e];
  part[p][be] = acc;
  __syncthreads();

  if (tid < 64) slog[be] = part[0][be] + part[1][be] + part[2][be] + part[3][be];
  __syncthreads();
  if (tid < 64) {
    float m = slog[b * 16];
    for (int j = 1; j < 16; ++j) m = fmaxf(m, slog[b * 16 + j]);
    sprob[be] = expf(slog[be] - m);
  }
  __syncthreads();
  if (tid < 4) {                            // tid = b
    float s = 0.0f;
    for (int j = 0; j < 16; ++j) s += sprob[tid * 16 + j];
    ssum[tid] = s;
    int i1 = 0; float v1 = -1.0f;
    for (int j = 0; j < 16; ++j) {
      float v = sprob[tid * 16 + j];
      if (v > v1) { v1 = v; i1 = j; }
    }
    int i2 = -1; float v2 = -1.0f;
    for (int j = 0; j < 16; ++j) {
      if (j == i1) continue;
      float v = sprob[tid * 16 + j];
      if (v > v2) { v2 = v; i2 = j; }
    }
    float inv = 1.0f / (v1 + v2);           // softmax denom cancels
    int* wsi = (int*)wsf;
    wsi[2 * tid]     = i1;  wsi[2 * tid + 1]     = i2;
    wsi[8 + 2 * tid] = tid; wsi[8 + 2 * tid + 1] = tid;
    wsf[16 + 2 * tid]     = v1 * inv;
    wsf[16 + 2 * tid + 1] = v2 * inv;
  }
  __syncthreads();
  if (tid == 0) {
    float kl = 0.0f;
    for (int j = 0; j < 16; ++j) {
      float pe = 0.25f * (sprob[j] / ssum[0] + sprob[16 + j] / ssum[1] +
                          sprob[32 + j] / ssum[2] + sprob[48 + j] / ssum[3]);
      kl += pe * logf(pe / (pe + 1e-7f) + 1e-7f);
    }
    out[524288] = -0.01f * kl;              // mi_loss
  }
}

// ---------------- wtrans: cw[e][oc][ic][tap] f32 -> frag-ordered bf16 -------
__global__ __launch_bounds__(256) void wtrans_kernel(const float* __restrict__ ctrl,
                                                     const float* __restrict__ cw1,
                                                     const float* __restrict__ cw2,
                                                     ushort* __restrict__ wt) {
  const int* wsi = (const int*)ctrl;
  int slot = blockIdx.y;
  int e = wsi[slot];
  int idx = blockIdx.x * 256 + threadIdx.x;   // < 294912
  int which = idx / 147456;
  int r = idx - which * 147456;
  int pos = r & 511;                          // lane*8 + j
  int chunk = r >> 9;                         // (tap*4+icc)*8 + blk
  int blk = chunk & 7;
  int t2 = chunk >> 3;
  int icc = t2 & 3, tap = t2 >> 2;
  int lane = pos >> 3, j = pos & 7;
  int oc = blk * 16 + (lane & 15);
  int ic = icc * 32 + (lane >> 4) * 8 + j;
  const float* src = which ? cw2 : cw1;
  wt[(size_t)slot * WT_ELEMS + idx] =
      f2bf(src[(((size_t)e * 128 + oc) * 128 + ic) * 9 + tap]);
}

// ---------------- prep: NCHW f32 (+spatial xform) -> NHWC bf16 --------------
__global__ __launch_bounds__(256) void prep_kernel(const float* __restrict__ ctrl,
                                                   const float* __restrict__ x,
                                                   ushort* __restrict__ buf0) {
  const int* wsi = (const int*)ctrl;
  int slot = blockIdx.y;
  int e = wsi[slot];
  int b = wsi[8 + slot];
  int tp = e % 3;
  int S = (tp == 0) ? 32 : ((tp == 1) ? 64 : 16);
  int chunk = blockIdx.x;
  if (chunk * 64 >= S * S) return;

  __shared__ float sT[128 * 65];
  int tid = threadIdx.x;
  const float* xb = x + (size_t)b * 131072;
  int pxl0 = tid & 63, c0 = tid >> 6;

  #pragma unroll 4
  for (int i = 0; i < 32; ++i) {
    int c = i * 4 + c0;
    int px = chunk * 64 + pxl0;
    float v;
    if (tp == 0) {
      v = xb[c * 1024 + px];
    } else if (tp == 1) {
      int h = px >> 6, w = px & 63;
      v = xb[c * 1024 + (h >> 1) * 32 + (w >> 1)];
    } else {
      int h = px >> 4, w = px & 15;
      const float* p = xb + c * 1024 + (h << 1) * 32 + (w << 1);
      v = fmaxf(fmaxf(p[0], p[1]), fmaxf(p[32], p[33]));
    }
    sT[c * 65 + pxl0] = v;
  }
  __syncthreads();
  ushort* ob = buf0 + (size_t)slot * SLOT_ELEMS;
  #pragma unroll
  for (int i = 0; i < 4; ++i) {
    int u = i * 256 + tid;
    int pxl = u >> 4, q = u & 15;
    bf16x8 pk;
    #pragma unroll
    for (int j = 0; j < 8; ++j) pk[j] = (short)f2bf(sT[(q * 8 + j) * 65 + pxl]);
    *(bf16x8*)&ob[(size_t)(chunk * 64 + pxl) * 128 + q * 8] = pk;
  }
}

// ---------------- conv3x3 via MFMA implicit GEMM ----------------------------
// block: 128 oc x 64 px (8x8 tile); 4 waves, each 32 oc x 64 px.
// A-frags (weights) streamed global->reg (frag-ordered, coalesced, L2-hot),
// double-buffered; B-frags (input) from LDS; K-loop barrier-free.
__global__ __launch_bounds__(256, 4) void conv_mfma(const float* __restrict__ ctrl,
                                                    const ushort* __restrict__ bufin,
                                                    ushort* __restrict__ bufout,
                                                    const ushort* __restrict__ wt,
                                                    int which,
                                                    const float* __restrict__ ball,
                                                    int gelu) {
  const int* wsi = (const int*)ctrl;
  int slot = blockIdx.x;
  int e = wsi[slot];
  int tp = e % 3;
  int S = (tp == 0) ? 32 : ((tp == 1) ? 64 : 16);
  int tpr = S >> 3;
  int tile = blockIdx.y;
  if (tile >= tpr * tpr) return;
  int tr = (tile / tpr) << 3;
  int tc = (tile % tpr) << 3;

  __shared__ ushort sIn[10 * 10 * 136];   // [halo px][128 ch + 8 pad]

  int tid = threadIdx.x;
  const ushort* in = bufin + (size_t)slot * SLOT_ELEMS;

  // stage input tile + halo (all 128 ch), zero padding — once per block
  for (int u = tid; u < 1600; u += 256) {
    int p = u >> 4, q = u & 15;
    int hr = p / 10, wc = p - hr * 10;
    int gh = tr + hr - 1, gw = tc + wc - 1;
    bf16x8 v = {0, 0, 0, 0, 0, 0, 0, 0};
    if (gh >= 0 && gh < S && gw >= 0 && gw < S)
      v = *(const bf16x8*)&in[(size_t)(gh * S + gw) * 128 + q * 8];
    *(bf16x8*)&sIn[p * 136 + q * 8] = v;
  }

  int wid = tid >> 6, lane = tid & 63;
  int ln = lane & 15, lg = lane >> 4;

  f32x4 acc[2][4];
  #pragma unroll
  for (int m = 0; m < 2; ++m)
    #pragma unroll
    for (int n = 0; n < 4; ++n)
      #pragma unroll
      for (int j = 0; j < 4; ++j) acc[m][n][j] = 0.0f;

  int pxb[4];
  #pragma unroll
  for (int n = 0; n < 4; ++n) {
    int px = n * 16 + ln;
    pxb[n] = (px >> 3) * 10 + (px & 7);
  }

  // wave's A-frag stream base: frag chunk = (k*8 + wid*2 + m)*512 elements
  const ushort* wbase = wt + (size_t)slot * WT_ELEMS + (size_t)which * 147456
                        + (size_t)(wid * 2) * 512 + lane * 8;

  __syncthreads();

  bf16x8 a_cur[2], a_nxt[2];
  a_cur[0] = *(const bf16x8*)&wbase[0];
  a_cur[1] = *(const bf16x8*)&wbase[512];

  #pragma unroll 4
  for (int kk = 0; kk < 36; ++kk) {         // k = tap*4 + icc
    int kn = (kk < 35) ? kk + 1 : 35;
    a_nxt[0] = *(const bf16x8*)&wbase[(size_t)kn * 4096];
    a_nxt[1] = *(const bf16x8*)&wbase[(size_t)kn * 4096 + 512];
    int tap = kk >> 2, icc = kk & 3;
    int off = (tap / 3) * 10 + (tap % 3);
    bf16x8 bfr[4];
    #pragma unroll
    for (int n = 0; n < 4; ++n)
      bfr[n] = *(bf16x8*)&sIn[(pxb[n] + off) * 136 + icc * 32 + lg * 8];
    #pragma unroll
    for (int m = 0; m < 2; ++m)
      #pragma unroll
      for (int n = 0; n < 4; ++n)
        acc[m][n] = __builtin_amdgcn_mfma_f32_16x16x32_bf16(a_cur[m], bfr[n],
                                                            acc[m][n], 0, 0, 0);
    a_cur[0] = a_nxt[0];
    a_cur[1] = a_nxt[1];
  }

  // epilogue: bias (+gelu), pack bf16, NHWC store
  ushort* outp = bufout + (size_t)slot * SLOT_ELEMS;
  const float* bias = ball + e * 128;
  int ocw = wid << 5;
  #pragma unroll
  for (int m = 0; m < 2; ++m) {
    int oc0 = ocw + m * 16 + lg * 4;
    float bv[4];
    #pragma unroll
    for (int j = 0; j < 4; ++j) bv[j] = bias[oc0 + j];
    #pragma unroll
    for (int n = 0; n < 4; ++n) {
      int px = n * 16 + ln;
      int gh = tr + (px >> 3), gw = tc + (px & 7);
      float v0 = acc[m][n][0] + bv[0];
      float v1 = acc[m][n][1] + bv[1];
      float v2 = acc[m][n][2] + bv[2];
      float v3 = acc[m][n][3] + bv[3];
      if (gelu) {
        v0 = 0.5f * v0 * (1.0f + erff(v0 * 0.70710678118654752f));
        v1 = 0.5f * v1 * (1.0f + erff(v1 * 0.70710678118654752f));
        v2 = 0.5f * v2 * (1.0f + erff(v2 * 0.70710678118654752f));
        v3 = 0.5f * v3 * (1.0f + erff(v3 * 0.70710678118654752f));
      }
      unsigned pk0 = (unsigned)f2bf(v0) | ((unsigned)f2bf(v1) << 16);
      unsigned pk1 = (unsigned)f2bf(v2) | ((unsigned)f2bf(v3) << 16);
      uint2 st; st.x = pk0; st.y = pk1;
      *(uint2*)&outp[(size_t)(gh * S + gw) * 128 + oc0] = st;
    }
  }
}

// ---------------- combine: post-transform * gate, NHWC bf16 -> NCHW f32 -----
__global__ __launch_bounds__(256) void combine_kernel(const float* __restrict__ ctrl,
                                                      const ushort* __restrict__ bufc,
                                                      float* __restrict__ out) {
  const int* wsi = (const int*)ctrl;
  int b = blockIdx.y, chunk = blockIdx.x;
  __shared__ float sO[64 * 129];
  int tid = threadIdx.x;

  #pragma unroll
  for (int i = 0; i < 4; ++i) {
    int u = i * 256 + tid;
    int pxl = u >> 4, q = u & 15;
    int px = chunk * 64 + pxl;
    int h = px >> 5, w = px & 31;
    float a8[8];
    #pragma unroll
    for (int j = 0; j < 8; ++j) a8[j] = 0.0f;

    for (int s = 0; s < 2; ++s) {
      int slot = 2 * b + s;
      int e = wsi[slot];
      float g = ctrl[16 + slot];
      int tp = e % 3;
      const ushort* cin = bufc + (size_t)slot * SLOT_ELEMS;
      if (tp == 0) {
        bf16x8 v = *(const bf16x8*)&cin[(size_t)(h * 32 + w) * 128 + q * 8];
        #pragma unroll
        for (int j = 0; j < 8; ++j) a8[j] += g * bf2f((ushort)v[j]);
      } else if (tp == 1) {                 // maxpool from 64x64
        bf16x8 v00 = *(const bf16x8*)&cin[(size_t)((2*h) * 64 + 2*w) * 128 + q * 8];
        bf16x8 v01 = *(const bf16x8*)&cin[(size_t)((2*h) * 64 + 2*w + 1) * 128 + q * 8];
        bf16x8 v10 = *(const bf16x8*)&cin[(size_t)((2*h+1) * 64 + 2*w) * 128 + q * 8];
        bf16x8 v11 = *(const bf16x8*)&cin[(size_t)((2*h+1) * 64 + 2*w + 1) * 128 + q * 8];
        #pragma unroll
        for (int j = 0; j < 8; ++j) {
          float mv = fmaxf(fmaxf(bf2f((ushort)v00[j]), bf2f((ushort)v01[j])),
                           fmaxf(bf2f((ushort)v10[j]), bf2f((ushort)v11[j])));
          a8[j] += g * mv;
        }
      } else {                              // bilinear up from 16x16
        float sh = h * 0.5f - 0.25f, sw = w * 0.5f - 0.25f;
        float fh0 = floorf(sh), fw0 = floorf(sw);
        int h0 = (int)fh0, w0 = (int)fw0;
        float fh = sh - fh0, fw = sw - fw0;
        int h0c = h0 < 0 ? 0 : h0, h1c = (h0 + 1 > 15) ? 15 : h0 + 1;
        int w0c = w0 < 0 ? 0 : w0, w1c = (w0 + 1 > 15) ? 15 : w0 + 1;
        bf16x8 v00 = *(const bf16x8*)&cin[(size_t)(h0c * 16 + w0c) * 128 + q * 8];
        bf16x8 v01 = *(const bf16x8*)&cin[(size_t)(h0c * 16 + w1c) * 128 + q * 8];
        bf16x8 v10 = *(const bf16x8*)&cin[(size_t)(h1c * 16 + w0c) * 128 + q * 8];
        bf16x8 v11 = *(const bf16x8*)&cin[(size_t)(h1c * 16 + w1c) * 128 + q * 8];
        #pragma unroll
        for (int j = 0; j < 8; ++j) {
          float vv = (1.0f - fh) * ((1.0f - fw) * bf2f((ushort)v00[j]) + fw * bf2f((ushort)v01[j])) +
                     fh * ((1.0f - fw) * bf2f((ushort)v10[j]) + fw * bf2f((ushort)v11[j]));
          a8[j] += g * vv;
        }
      }
    }
    #pragma unroll
    for (int j = 0; j < 8; ++j) sO[pxl * 129 + q * 8 + j] = a8[j];
  }
  __syncthreads();
  float* ob = out + (size_t)b * 131072;
  #pragma unroll 4
  for (int i = 0; i < 32; ++i) {
    int u = i * 256 + tid;
    int c = u >> 6, pxl = u & 63;
    ob[(size_t)c * 1024 + chunk * 64 + pxl] = sO[pxl * 129 + c];
  }
}

// ---------------------------------------------------------------------------
extern "C" void kernel_launch(void* const* d_in, const int* in_sizes, int n_in,
                              void* d_out, int out_size, void* d_ws, size_t ws_size,
                              hipStream_t stream) {
  const float* x   = (const float*)d_in[0];
  const float* tf  = (const float*)d_in[1];
  const float* Wx  = (const float*)d_in[2];
  const float* Wt  = (const float*)d_in[3];
  const float* cw1 = (const float*)d_in[4];
  const float* cb1 = (const float*)d_in[5];
  const float* cw2 = (const float*)d_in[6];
  const float* cb2 = (const float*)d_in[7];
  float* out = (float*)d_out;

  float*  wsf  = (float*)d_ws;
  ushort* wt2  = (ushort*)(wsf + 1024);
  ushort* buf0 = wt2 + 8 * (size_t)WT_ELEMS;
  ushort* buf1 = buf0 + 8 * (size_t)SLOT_ELEMS;

  hipLaunchKernelGGL(xp_kernel,      dim3(512),     dim3(256), 0, stream, x, wsf);
  hipLaunchKernelGGL(gate_kernel,    dim3(1),       dim3(256), 0, stream, tf, Wx, Wt, wsf, out);
  hipLaunchKernelGGL(wtrans_kernel,  dim3(1152, 8), dim3(256), 0, stream, wsf, cw1, cw2, wt2);
  hipLaunchKernelGGL(prep_kernel,    dim3(64, 8),   dim3(256), 0, stream, wsf, x, buf0);
  hipLaunchKernelGGL(conv_mfma,      dim3(8, 64),   dim3(256), 0, stream, wsf, buf0, buf1, wt2, 0, cb1, 1);
  hipLaunchKernelGGL(conv_mfma,      dim3(8, 64),   dim3(256), 0, stream, wsf, buf1, buf0, wt2, 1, cb2, 0);
  hipLaunchKernelGGL(combine_kernel, dim3(16, 4),   dim3(256), 0, stream, wsf, buf0, out);
}